// Round 2
// baseline (270.914 us; speedup 1.0000x reference)
//
#include <hip/hip_runtime.h>

// Kernel 1: E[b] = expm(t[b] * A), A = 0.5*(B - B^T), B = M + M0, 8x8.
// One block (64 threads) per t value; thread `lane` owns element (i,j) with
// i = lane>>3, j = lane&7. Taylor series: term_{k} = term_{k-1} * (tA) / k.
// ||tA||_F <~ 0.1 so 12 terms is exact to fp32 roundoff.
__global__ void expm_kernel(const float* __restrict__ M, const float* __restrict__ M0,
                            const float* __restrict__ t, float* __restrict__ E) {
    const int b = blockIdx.x;
    const int lane = threadIdx.x;            // 0..63
    const int i = lane >> 3;
    const int j = lane & 7;

    __shared__ float sA[64];                 // tA
    __shared__ float sP[64];                 // current Taylor term

    const float bij = M[i * 8 + j] + M0[i * 8 + j];
    const float bji = M[j * 8 + i] + M0[j * 8 + i];
    const float ta = t[b] * 0.5f * (bij - bji);

    sA[lane] = ta;
    float e = (i == j ? 1.0f : 0.0f) + ta;   // I + tA
    float p = ta;
    __syncthreads();

    for (int k = 2; k <= 12; ++k) {
        sP[lane] = p;
        __syncthreads();
        float s = 0.0f;
        #pragma unroll
        for (int l = 0; l < 8; ++l) {
            s = fmaf(sP[i * 8 + l], sA[l * 8 + j], s);
        }
        p = s * (1.0f / (float)k);
        e += p;
        __syncthreads();                     // protect sP before next overwrite
    }

    E[b * 64 + lane] = e;
}

// Kernel 2: out[t, n, i] = sum_j E[t][i][j] * x[n][j].
//
// v3: loop-nest inversion to kill read amplification. v1/v2 put t in
// blockIdx.y, so every t-slice re-read ALL of x: 512 KB x 512 t = 256 MiB of
// logical reads, equal to the mandatory write traffic. The 256 MiB write
// stream washes the 4 MiB per-XCD L2s (and L3), so those re-reads cost real
// bandwidth -> both prior versions pinned at ~2.9 TB/s (~2x roofline time),
// invariant to store-pattern changes.
//
// Now each block owns a fixed 1024-row x-chunk, loaded ONCE into registers
// (4 rows/thread x 32 B), and iterates over TBLK=8 t-values: stage E_t from
// LDS into registers (broadcast reads, conflict-free), 256 FMAs, 32 KB of
// contiguous stores. Aggregate x reads: 256 MiB -> 512 KB x 64 t-groups
// = 32 MB. E total 128 KB. The kernel becomes a near-pure write stream,
// the pattern the harness fill sustains 6.5 TB/s with.
#define BLOCK 256
#define RPT 4          // x rows per thread held in registers
#define TBLK 8         // t values per block

__global__ __launch_bounds__(BLOCK) void apply_kernel(const float* __restrict__ Eall,
                                                      const float* __restrict__ x,
                                                      float* __restrict__ out,
                                                      int N, int T) {
    const int tid = threadIdx.x;
    const int n0 = blockIdx.x * (BLOCK * RPT);
    const int t0 = blockIdx.y * TBLK;

    // Stage this block's TBLK E-matrices into LDS (2 KB), coalesced.
    __shared__ float sE[TBLK * 64];
    #pragma unroll
    for (int c = tid; c < TBLK * 64; c += BLOCK) {
        const int t = t0 + (c >> 6);
        sE[c] = (t < T) ? Eall[t * 64 + (c & 63)] : 0.0f;
    }

    // Load this thread's x rows into registers, once.
    const float4* __restrict__ x4 = (const float4*)x;
    float xr[RPT][8];
    bool valid[RPT];
    #pragma unroll
    for (int g = 0; g < RPT; ++g) {
        const int n = n0 + g * BLOCK + tid;
        valid[g] = (n < N);
        if (valid[g]) {
            const float4 a = x4[2 * n];
            const float4 b = x4[2 * n + 1];
            xr[g][0] = a.x; xr[g][1] = a.y; xr[g][2] = a.z; xr[g][3] = a.w;
            xr[g][4] = b.x; xr[g][5] = b.y; xr[g][6] = b.z; xr[g][7] = b.w;
        } else {
            #pragma unroll
            for (int jj = 0; jj < 8; ++jj) xr[g][jj] = 0.0f;
        }
    }
    __syncthreads();

    for (int tt = 0; tt < TBLK; ++tt) {
        const int t = t0 + tt;
        if (t >= T) break;

        // E_t: LDS -> registers. All lanes read the same address per
        // instruction -> broadcast, conflict-free; b128 reads.
        float e[64];
        #pragma unroll
        for (int q = 0; q < 16; ++q) {
            const float4 v = *(const float4*)&sE[tt * 64 + q * 4];
            e[q * 4 + 0] = v.x; e[q * 4 + 1] = v.y;
            e[q * 4 + 2] = v.z; e[q * 4 + 3] = v.w;
        }

        float4* __restrict__ o4 = (float4*)(out + (size_t)t * (size_t)N * 8);
        #pragma unroll
        for (int g = 0; g < RPT; ++g) {
            if (valid[g]) {
                const int n = n0 + g * BLOCK + tid;
                float y[8];
                #pragma unroll
                for (int ii = 0; ii < 8; ++ii) {
                    float s = 0.0f;
                    #pragma unroll
                    for (int jj = 0; jj < 8; ++jj) {
                        s = fmaf(e[ii * 8 + jj], xr[g][jj], s);
                    }
                    y[ii] = s;
                }
                o4[2 * n]     = make_float4(y[0], y[1], y[2], y[3]);
                o4[2 * n + 1] = make_float4(y[4], y[5], y[6], y[7]);
            }
        }
    }
}

extern "C" void kernel_launch(void* const* d_in, const int* in_sizes, int n_in,
                              void* d_out, int out_size, void* d_ws, size_t ws_size,
                              hipStream_t stream) {
    const float* x  = (const float*)d_in[0];   // [N, 8]
    const float* t  = (const float*)d_in[1];   // [T]
    const float* M  = (const float*)d_in[2];   // [8, 8]
    const float* M0 = (const float*)d_in[3];   // [8, 8]
    float* out = (float*)d_out;                // [T, N, 8]
    float* E = (float*)d_ws;                   // [T, 64] scratch (T*256 bytes)

    const int N = in_sizes[0] / 8;
    const int T = in_sizes[1];

    hipLaunchKernelGGL(expm_kernel, dim3(T), dim3(64), 0, stream, M, M0, t, E);

    const int gx = (N + BLOCK * RPT - 1) / (BLOCK * RPT);   // n-chunks
    const int gy = (T + TBLK - 1) / TBLK;                   // t-groups
    hipLaunchKernelGGL(apply_kernel, dim3(gx, gy), dim3(BLOCK), 0, stream, E, x, out, N, T);
}